// Round 2
// baseline (102.353 us; speedup 1.0000x reference)
//
#include <hip/hip_runtime.h>

// IF neuron: v += x[t]; out = (v >= TH) ? TH : 0; v -= out;  over T=4 steps.
// x: [T=4, B=32, H=512, W=1024] fp32. Streaming, memory-bound.
// 536.9 MB total HBM traffic -> ~85 us at the 6.29 TB/s copy ceiling.
//
// R1 -> R2 changes:
//  - grid-stride with 2048 persistent blocks (Guideline 11)
//  - all 4 timestep loads issued before any dependent compute (MLP=4)
//  - nontemporal loads+stores: data is touched exactly once, working set
//    (512 MiB) is 2x L3 -> bypass cache allocate overhead

#define TH 1.0f

typedef float f32x4 __attribute__((ext_vector_type(4)));

__global__ __launch_bounds__(256) void IFNeuron_90048284328050_kernel(
    const f32x4* __restrict__ x, f32x4* __restrict__ out, int nvec) {
    const size_t stride = (size_t)gridDim.x * blockDim.x;
    const size_t nv = (size_t)nvec;

    for (size_t i = (size_t)blockIdx.x * blockDim.x + threadIdx.x; i < nv;
         i += stride) {
        // issue all 4 independent loads first (4 outstanding VMEM ops)
        f32x4 x0 = __builtin_nontemporal_load(&x[i]);
        f32x4 x1 = __builtin_nontemporal_load(&x[nv + i]);
        f32x4 x2 = __builtin_nontemporal_load(&x[2 * nv + i]);
        f32x4 x3 = __builtin_nontemporal_load(&x[3 * nv + i]);

        f32x4 v = x0;
        f32x4 o0, o1, o2, o3;
        o0.x = (v.x >= TH) ? TH : 0.f;
        o0.y = (v.y >= TH) ? TH : 0.f;
        o0.z = (v.z >= TH) ? TH : 0.f;
        o0.w = (v.w >= TH) ? TH : 0.f;
        v = v - o0 + x1;
        o1.x = (v.x >= TH) ? TH : 0.f;
        o1.y = (v.y >= TH) ? TH : 0.f;
        o1.z = (v.z >= TH) ? TH : 0.f;
        o1.w = (v.w >= TH) ? TH : 0.f;
        v = v - o1 + x2;
        o2.x = (v.x >= TH) ? TH : 0.f;
        o2.y = (v.y >= TH) ? TH : 0.f;
        o2.z = (v.z >= TH) ? TH : 0.f;
        o2.w = (v.w >= TH) ? TH : 0.f;
        v = v - o2 + x3;
        o3.x = (v.x >= TH) ? TH : 0.f;
        o3.y = (v.y >= TH) ? TH : 0.f;
        o3.z = (v.z >= TH) ? TH : 0.f;
        o3.w = (v.w >= TH) ? TH : 0.f;

        __builtin_nontemporal_store(o0, &out[i]);
        __builtin_nontemporal_store(o1, &out[nv + i]);
        __builtin_nontemporal_store(o2, &out[2 * nv + i]);
        __builtin_nontemporal_store(o3, &out[3 * nv + i]);
    }
}

extern "C" void kernel_launch(void* const* d_in, const int* in_sizes, int n_in,
                              void* d_out, int out_size, void* d_ws, size_t ws_size,
                              hipStream_t stream) {
    const f32x4* x = (const f32x4*)d_in[0];
    f32x4* out = (f32x4*)d_out;

    const int T = 4;
    int total = in_sizes[0];            // 67,108,864 floats
    int nvec = (total / T) / 4;         // 4,194,304 float4 per timestep

    int block = 256;
    int grid = 2048;                    // persistent blocks, grid-stride (8 iters/thread)
    IFNeuron_90048284328050_kernel<<<grid, block, 0, stream>>>(x, out, nvec);
}